// Round 15
// baseline (145.939 us; speedup 1.0000x reference)
//
#include <hip/hip_runtime.h>
#include <math.h>

#define B_SZ 64
#define NCH 32
#define NPX 20000
#define BETA_C 1.3130352854993312f  // 1/tanh(1)
#define NCHUNKS 625                 // 32-pixel chunks
#define OB 25                       // blocks per batch (both compute kernels)
#define CPB 25                      // chunks per block (25*25 = 625 exactly)

typedef _Float16 f16;
typedef __attribute__((ext_vector_type(2)))  f16   h2;
typedef __attribute__((ext_vector_type(4)))  f16   h4;
typedef __attribute__((ext_vector_type(8)))  f16   h8;
typedef __attribute__((ext_vector_type(16))) float f32x16;
typedef __attribute__((ext_vector_type(8)))  short short8;

// cvt_pkrtz returns __fp16x2; bit_cast to our _Float16x2 (same 4-byte layout)
__device__ __forceinline__ h2 pk_f16(float a, float b) {
    return __builtin_bit_cast(h2, __builtin_amdgcn_cvt_pkrtz(a, b));
}

// ---------------------------------------------------------------------------
// Prep: A (f32 [c][p]) -> f16 [c][p] planes;  D (f32 [c][p]) -> f16 [p][c].
// Blocks [0,1250): A conversion. Blocks [1250,1329): D transpose.
// ---------------------------------------------------------------------------
__global__ __launch_bounds__(256) void prep_kernel(
    const float* __restrict__ A_real, const float* __restrict__ A_imag,
    const float* __restrict__ D_real, const float* __restrict__ D_imag,
    f16* __restrict__ Ah_r, f16* __restrict__ Ah_i,
    f16* __restrict__ Dth_r, f16* __restrict__ Dth_i)
{
    __shared__ float s[NCH][257];
    const int t = threadIdx.x;
    const int bx = blockIdx.x;
    if (bx < 1250) {
        const int f = (bx * 256 + t) * 4;
        const int N = NCH * NPX;
        const float* src; f16* dst; int off;
        if (f < N) { src = A_real; dst = Ah_r; off = f; }
        else       { src = A_imag; dst = Ah_i; off = f - N; }
        const float4 v = *(const float4*)(src + off);
        h4 o = { (f16)v.x, (f16)v.y, (f16)v.z, (f16)v.w };
        *(h4*)(dst + off) = o;
        return;
    }
    const int p = (bx - 1250) * 256 + t;
    for (int plane = 0; plane < 2; ++plane) {
        const float* src = plane ? D_imag : D_real;
        f16* dst = plane ? Dth_i : Dth_r;
        __syncthreads();
        for (int c = 0; c < NCH; ++c)
            if (p < NPX) s[c][t] = src[(size_t)c * NPX + p];
        __syncthreads();
        if (p < NPX) {
#pragma unroll
            for (int q = 0; q < 4; ++q) {
                h8 wv;
#pragma unroll
                for (int e = 0; e < 8; ++e) wv[e] = (f16)s[q * 8 + e][t];
                *(h8*)(dst + (size_t)p * NCH + q * 8) = wv;
            }
        }
    }
}

// ---------------------------------------------------------------------------
// Kernel 1: latent via 32x32x16 f16 MFMA, 32-px chunks, ~6 chunks/wave.
//   A-op: S[c'=l&31][k=16h+8*(l>>5)+j], B-op: Dt[p=p0+(l&31)][same k]
//   C/D : T[row=(r&3)+8*(r>>2)+4*(l>>5)][col=l&31]   (m74/m101-verified)
// ---------------------------------------------------------------------------
__global__ __launch_bounds__(256) void latent_mfma(
    const float* __restrict__ S_real, const float* __restrict__ S_imag,
    const float* __restrict__ tau,
    const f16* __restrict__ Dth_r, const f16* __restrict__ Dth_i,
    float* __restrict__ lam_out)
{
    const int b   = blockIdx.y;
    const int t   = threadIdx.x;
    const int w   = t >> 6;
    const int l   = t & 63;
    const int l31 = l & 31;
    const int kh  = l >> 5;

    // S fragments, f16, once per block
    const float* srp = S_real + (size_t)b * 1024 + l31 * 32 + 8 * kh;
    const float* sip = S_imag + (size_t)b * 1024 + l31 * 32 + 8 * kh;
    h8 Sr0, Sr1, Si0, Si1, nSi0, nSi1;
#pragma unroll
    for (int j = 0; j < 8; ++j) {
        Sr0[j] = (f16)srp[j];      Sr1[j] = (f16)srp[16 + j];
        const float v0 = sip[j], v1 = sip[16 + j];
        Si0[j]  = (f16)v0;   Si1[j]  = (f16)v1;
        nSi0[j] = (f16)(-v0); nSi1[j] = (f16)(-v1);
    }

    const int base = blockIdx.x * CPB;
    const int end  = min(NCHUNKS, base + CPB);
    for (int ci = base + w; ci < end; ci += 4) {
        const int p0 = ci * 32;
        const int p  = p0 + l31;

        const f16* dbr = Dth_r + (size_t)p * 32 + 8 * kh;
        const f16* dbi = Dth_i + (size_t)p * 32 + 8 * kh;
        const h8 Dr0 = *(const h8*)(dbr);
        const h8 Dr1 = *(const h8*)(dbr + 16);
        const h8 Di0 = *(const h8*)(dbi);
        const h8 Di1 = *(const h8*)(dbi + 16);

        f32x16 Tr = {}, Ti = {};
        Tr = __builtin_amdgcn_mfma_f32_32x32x16_f16(Sr0,  Dr0, Tr, 0, 0, 0);
        Ti = __builtin_amdgcn_mfma_f32_32x32x16_f16(Sr0,  Di0, Ti, 0, 0, 0);
        Tr = __builtin_amdgcn_mfma_f32_32x32x16_f16(Sr1,  Dr1, Tr, 0, 0, 0);
        Ti = __builtin_amdgcn_mfma_f32_32x32x16_f16(Sr1,  Di1, Ti, 0, 0, 0);
        Tr = __builtin_amdgcn_mfma_f32_32x32x16_f16(nSi0, Di0, Tr, 0, 0, 0);
        Ti = __builtin_amdgcn_mfma_f32_32x32x16_f16(Si0,  Dr0, Ti, 0, 0, 0);
        Tr = __builtin_amdgcn_mfma_f32_32x32x16_f16(nSi1, Di1, Tr, 0, 0, 0);
        Ti = __builtin_amdgcn_mfma_f32_32x32x16_f16(Si1,  Dr1, Ti, 0, 0, 0);

        // dot with d (lane rows R = (r&3)+8*(r>>2)+4*kh, col = p)
        const f16* ddr = Dth_r + (size_t)p * 32 + 4 * kh;
        const f16* ddi = Dth_i + (size_t)p * 32 + 4 * kh;
        float part0 = 0.f, part1 = 0.f;
#pragma unroll
        for (int g = 0; g < 4; ++g) {
            const h4 dr = *(const h4*)(ddr + g * 8);
            const h4 di = *(const h4*)(ddi + g * 8);
#pragma unroll
            for (int r = 0; r < 4; ++r) {
                part0 = fmaf((float)dr[r], Tr[4 * g + r], part0);
                part1 = fmaf((float)di[r], Ti[4 * g + r], part1);
            }
        }
        float part = part0 + part1;
        part += __shfl_xor(part, 32, 64);

        const float lat = part - tau[p];
        const float lc  = fminf(fmaxf(lat, -15.f), 15.f);
        const float e   = __expf(2.f * lc);
        const float th  = __fdividef(e - 1.f, e + 1.f);
        const float lam = fmaxf(1e-6f, BETA_C * th);
        if (l < 32) lam_out[(size_t)b * NPX + p] = lam;
    }
}

// ---------------------------------------------------------------------------
// Kernel 2: partial out_b = A diag(lam) A^H, ~6 chunks/wave.
// Partials (mapped to (orow,col) order) stored to ws — NO atomics.
// ---------------------------------------------------------------------------
__global__ __launch_bounds__(256) void outer_mfma(
    const f16* __restrict__ Ah_r, const f16* __restrict__ Ah_i,
    const float* __restrict__ lam_in, float* __restrict__ part)
{
    __shared__ float red[4][64][17];
    const int b   = blockIdx.y;
    const int t   = threadIdx.x;
    const int w   = t >> 6;
    const int l   = t & 63;
    const int row = l & 31;
    const int kh  = l >> 5;

    f32x16 accRe = {}, accIm = {};

    const int base = blockIdx.x * CPB;
    const int end  = min(NCHUNKS, base + CPB);
    for (int ci = base + w; ci < end; ci += 4) {
        const int p0 = ci * 32;
        const int pk = p0 + 8 * kh;

        const f16* ar_p = Ah_r + (size_t)row * NPX + pk;
        const f16* ai_p = Ah_i + (size_t)row * NPX + pk;
        const h8 ar0 = *(const h8*)(ar_p);
        const h8 ar1 = *(const h8*)(ar_p + 16);
        const h8 ai0 = *(const h8*)(ai_p);
        const h8 ai1 = *(const h8*)(ai_p + 16);

        const float* lp = lam_in + (size_t)b * NPX + pk;
        const float4 la = *(const float4*)(lp);
        const float4 lb = *(const float4*)(lp + 4);
        const float4 lc = *(const float4*)(lp + 16);
        const float4 ld = *(const float4*)(lp + 20);
        const h2 q0 = pk_f16(la.x, la.y);
        const h2 q1 = pk_f16(la.z, la.w);
        const h2 q2 = pk_f16(lb.x, lb.y);
        const h2 q3 = pk_f16(lb.z, lb.w);
        const h2 q4 = pk_f16(lc.x, lc.y);
        const h2 q5 = pk_f16(lc.z, lc.w);
        const h2 q6 = pk_f16(ld.x, ld.y);
        const h2 q7 = pk_f16(ld.z, ld.w);
        const h8 lam0 = {q0[0], q0[1], q1[0], q1[1], q2[0], q2[1], q3[0], q3[1]};
        const h8 lam1 = {q4[0], q4[1], q5[0], q5[1], q6[0], q6[1], q7[0], q7[1]};

        const h8 vr0 = ar0 * lam0;   // v_pk_mul_f16 x4 each
        const h8 vi0 = ai0 * lam0;
        const h8 vr1 = ar1 * lam1;
        const h8 vi1 = ai1 * lam1;
        const h8 nvr0 = __builtin_bit_cast(h8, __builtin_bit_cast(short8, vr0) ^ (short)0x8000);
        const h8 nvr1 = __builtin_bit_cast(h8, __builtin_bit_cast(short8, vr1) ^ (short)0x8000);

        accRe = __builtin_amdgcn_mfma_f32_32x32x16_f16(vr0,  ar0, accRe, 0, 0, 0);
        accIm = __builtin_amdgcn_mfma_f32_32x32x16_f16(vi0,  ar0, accIm, 0, 0, 0);
        accRe = __builtin_amdgcn_mfma_f32_32x32x16_f16(vi0,  ai0, accRe, 0, 0, 0);
        accIm = __builtin_amdgcn_mfma_f32_32x32x16_f16(nvr0, ai0, accIm, 0, 0, 0);
        accRe = __builtin_amdgcn_mfma_f32_32x32x16_f16(vr1,  ar1, accRe, 0, 0, 0);
        accIm = __builtin_amdgcn_mfma_f32_32x32x16_f16(vi1,  ar1, accIm, 0, 0, 0);
        accRe = __builtin_amdgcn_mfma_f32_32x32x16_f16(vi1,  ai1, accRe, 0, 0, 0);
        accIm = __builtin_amdgcn_mfma_f32_32x32x16_f16(nvr1, ai1, accIm, 0, 0, 0);
    }

    // cross-wave reduce, then plain stores of the mapped partial (no atomics)
    float* pb = part + ((size_t)b * OB + blockIdx.x) * 2048;
#pragma unroll
    for (int r = 0; r < 16; ++r) red[w][l][r] = accRe[r];
    __syncthreads();
#pragma unroll
    for (int q = 0; q < 4; ++q) {
        const int idx = t + 256 * q;
        const int ll = idx >> 4, rr = idx & 15;
        const float s = red[0][ll][rr] + red[1][ll][rr] + red[2][ll][rr] + red[3][ll][rr];
        const int col  = ll & 31;
        const int orow = (rr & 3) + 8 * (rr >> 2) + 4 * (ll >> 5);
        pb[orow * 32 + col] = s;
    }
    __syncthreads();
#pragma unroll
    for (int r = 0; r < 16; ++r) red[w][l][r] = accIm[r];
    __syncthreads();
#pragma unroll
    for (int q = 0; q < 4; ++q) {
        const int idx = t + 256 * q;
        const int ll = idx >> 4, rr = idx & 15;
        const float s = red[0][ll][rr] + red[1][ll][rr] + red[2][ll][rr] + red[3][ll][rr];
        const int col  = ll & 31;
        const int orow = (rr & 3) + 8 * (rr >> 2) + 4 * (ll >> 5);
        pb[1024 + orow * 32 + col] = s;
    }
}

// ---------------------------------------------------------------------------
// Kernel 3: sum the OB partials per batch -> out planes (coalesced).
// ---------------------------------------------------------------------------
__global__ __launch_bounds__(256) void reduce_kernel(
    const float* __restrict__ part,
    float* __restrict__ out_re, float* __restrict__ out_im)
{
    const int b = blockIdx.x;
    const int t = threadIdx.x;
#pragma unroll
    for (int q = 0; q < 4; ++q) {
        const int slot = q * 256 + t;
        float sr = 0.f, si = 0.f;
        for (int k = 0; k < OB; ++k) {
            const float* pb = part + ((size_t)b * OB + k) * 2048;
            sr += pb[slot];
            si += pb[1024 + slot];
        }
        out_re[(size_t)b * 1024 + slot] = sr;
        if (out_im) out_im[(size_t)b * 1024 + slot] = si;
    }
}

// ---------------------------------------------------------------------------
extern "C" void kernel_launch(void* const* d_in, const int* in_sizes, int n_in,
                              void* d_out, int out_size, void* d_ws, size_t ws_size,
                              hipStream_t stream) {
    const float* S_real = (const float*)d_in[0];
    const float* S_imag = (const float*)d_in[1];
    const float* tau    = (const float*)d_in[2];
    const float* D_real = (const float*)d_in[3];
    const float* D_imag = (const float*)d_in[4];
    const float* A_real = (const float*)d_in[5];
    const float* A_imag = (const float*)d_in[6];

    // ws: Ah_r | Ah_i | Dth_r | Dth_i (f16, 5.12 MB) | partials (13.1 MB)
    f16* Ah_r  = (f16*)d_ws;
    f16* Ah_i  = Ah_r + (size_t)NCH * NPX;
    f16* Dth_r = Ah_i + (size_t)NCH * NPX;
    f16* Dth_i = Dth_r + (size_t)NCH * NPX;
    float* part = (float*)(Dth_i + (size_t)NCH * NPX);

    const size_t LAT = (size_t)B_SZ * NPX;        // 1,280,000
    const size_t RE  = (size_t)B_SZ * NCH * NCH;  // 65,536
    const size_t lam_off = (size_t)out_size - LAT;
    float* out_re = (float*)d_out;
    float* lam    = out_re + lam_off;
    float* out_im = (lam_off >= 2 * RE) ? out_re + RE : nullptr;

    prep_kernel<<<dim3(1250 + 79), 256, 0, stream>>>(
        A_real, A_imag, D_real, D_imag, Ah_r, Ah_i, Dth_r, Dth_i);

    latent_mfma<<<dim3(OB, B_SZ), 256, 0, stream>>>(
        S_real, S_imag, tau, Dth_r, Dth_i, lam);

    outer_mfma<<<dim3(OB, B_SZ), 256, 0, stream>>>(
        Ah_r, Ah_i, lam, part);

    reduce_kernel<<<dim3(B_SZ), 256, 0, stream>>>(part, out_re, out_im);
}

// Round 16
// 127.923 us; speedup vs baseline: 1.1408x; 1.1408x over previous
//
#include <hip/hip_runtime.h>
#include <math.h>

#define B_SZ 64
#define NCH 32
#define NPX 20000
#define BETA_C 1.3130352854993312f  // 1/tanh(1)
#define NCHUNKS 625                 // 32-pixel chunks
#define OB 25                       // blocks per batch (both compute kernels)
#define CPB 25                      // chunks per block (25*25 = 625 exactly)

typedef _Float16 f16;
typedef __attribute__((ext_vector_type(2)))  f16   h2;
typedef __attribute__((ext_vector_type(4)))  f16   h4;
typedef __attribute__((ext_vector_type(8)))  f16   h8;
typedef __attribute__((ext_vector_type(16))) float f32x16;
typedef __attribute__((ext_vector_type(8)))  short short8;

__device__ __forceinline__ h2 pk_f16(float a, float b) {
    return __builtin_bit_cast(h2, __builtin_amdgcn_cvt_pkrtz(a, b));
}

// ---------------------------------------------------------------------------
// Prep: build MFMA-fragment-ordered f16 copies (all hot-loop loads coalesced).
//   Dfrag[ci][g][l31][e]  = D[8g+e][ci*32+l31]   (latent B-op: lane=pixel)
//   Afrag[ci][pb][l31][e] = A[l31][ci*32+8pb+e]  (outer A/B-op: lane=channel)
// 79 blocks x 256 threads; 4 staging rounds (Ar, Ai, Dr, Di) via LDS.
// ---------------------------------------------------------------------------
__global__ __launch_bounds__(256) void prep_kernel(
    const float* __restrict__ A_real, const float* __restrict__ A_imag,
    const float* __restrict__ D_real, const float* __restrict__ D_imag,
    f16* __restrict__ AfR, f16* __restrict__ AfI,
    f16* __restrict__ DfR, f16* __restrict__ DfI)
{
    __shared__ float s[NCH][257];
    const int t  = threadIdx.x;
    const int bx = blockIdx.x;
    const int p  = bx * 256 + t;
    const int lc = t >> 5;              // chunk-local index 0..7
    const int ci = bx * 8 + lc;
    const int c31 = t & 31;

    for (int plane = 0; plane < 4; ++plane) {
        const float* src = (plane == 0) ? A_real : (plane == 1) ? A_imag
                         : (plane == 2) ? D_real : D_imag;
        __syncthreads();
        for (int c = 0; c < NCH; ++c)
            if (p < NPX) s[c][t] = src[(size_t)c * NPX + p];
        __syncthreads();
        if (ci >= NCHUNKS) continue;
        if (plane < 2) {
            // A: thread = (chunk lc, channel c31); read s[c31][lc*32+8pb+e]
            f16* dst = (plane == 0) ? AfR : AfI;
#pragma unroll
            for (int pb = 0; pb < 4; ++pb) {
                h8 wv;
#pragma unroll
                for (int e = 0; e < 8; ++e)
                    wv[e] = (f16)s[c31][lc * 32 + pb * 8 + e];
                *(h8*)(dst + (((size_t)ci * 4 + pb) * 32 + c31) * 8) = wv;
            }
        } else {
            // D: thread = pixel t; read s[8g+e][t]
            f16* dst = (plane == 2) ? DfR : DfI;
#pragma unroll
            for (int g = 0; g < 4; ++g) {
                h8 wv;
#pragma unroll
                for (int e = 0; e < 8; ++e)
                    wv[e] = (f16)s[g * 8 + e][t];
                *(h8*)(dst + (((size_t)ci * 4 + g) * 32 + c31) * 8) = wv;
            }
        }
    }
}

// ---------------------------------------------------------------------------
// Kernel 1: latent via 32x32x16 f16 MFMA. S from padded LDS (stride 33,
// bank-conflict-free); D fragments coalesced (1KB/wave-load).
//   C/D : T[row=(r&3)+8*(r>>2)+4*kh][col=l31]   (m74/m101-verified)
// ---------------------------------------------------------------------------
__global__ __launch_bounds__(256) void latent_mfma(
    const float* __restrict__ S_real, const float* __restrict__ S_imag,
    const float* __restrict__ tau,
    const f16* __restrict__ DfR, const f16* __restrict__ DfI,
    float* __restrict__ lam_out)
{
    __shared__ float sre[NCH * 33], sim[NCH * 33];
    const int b   = blockIdx.y;
    const int t   = threadIdx.x;
    const int w   = t >> 6;
    const int l   = t & 63;
    const int l31 = l & 31;
    const int kh  = l >> 5;

    // stage S coalesced (1024 f32 per plane)
    for (int i = t; i < NCH * NCH; i += 256) {
        const int c = i >> 5, k = i & 31;
        sre[c * 33 + k] = S_real[(size_t)b * 1024 + i];
        sim[c * 33 + k] = S_imag[(size_t)b * 1024 + i];
    }
    __syncthreads();

    // fragments from LDS (addr stride 33 across lanes -> conflict-free)
    const int i0 = l31 * 33 + 8 * kh;
    h8 Sr0, Sr1, Si0, Si1, nSi0, nSi1;
#pragma unroll
    for (int j = 0; j < 8; ++j) {
        Sr0[j] = (f16)sre[i0 + j];
        Sr1[j] = (f16)sre[i0 + 16 + j];
        const float v0 = sim[i0 + j], v1 = sim[i0 + 16 + j];
        Si0[j]  = (f16)v0;   Si1[j]  = (f16)v1;
        nSi0[j] = (f16)(-v0); nSi1[j] = (f16)(-v1);
    }

    const int base = blockIdx.x * CPB;
    const int end  = min(NCHUNKS, base + CPB);
    for (int ci = base + w; ci < end; ci += 4) {
        const size_t cb = (size_t)ci * 1024;   // f16 elems per chunk block
        const h8 Dr0 = *(const h8*)(DfR + cb + l * 8);
        const h8 Dr1 = *(const h8*)(DfR + cb + 512 + l * 8);
        const h8 Di0 = *(const h8*)(DfI + cb + l * 8);
        const h8 Di1 = *(const h8*)(DfI + cb + 512 + l * 8);

        f32x16 Tr = {}, Ti = {};
        Tr = __builtin_amdgcn_mfma_f32_32x32x16_f16(Sr0,  Dr0, Tr, 0, 0, 0);
        Ti = __builtin_amdgcn_mfma_f32_32x32x16_f16(Sr0,  Di0, Ti, 0, 0, 0);
        Tr = __builtin_amdgcn_mfma_f32_32x32x16_f16(Sr1,  Dr1, Tr, 0, 0, 0);
        Ti = __builtin_amdgcn_mfma_f32_32x32x16_f16(Sr1,  Di1, Ti, 0, 0, 0);
        Tr = __builtin_amdgcn_mfma_f32_32x32x16_f16(nSi0, Di0, Tr, 0, 0, 0);
        Ti = __builtin_amdgcn_mfma_f32_32x32x16_f16(Si0,  Dr0, Ti, 0, 0, 0);
        Tr = __builtin_amdgcn_mfma_f32_32x32x16_f16(nSi1, Di1, Tr, 0, 0, 0);
        Ti = __builtin_amdgcn_mfma_f32_32x32x16_f16(Si1,  Dr1, Ti, 0, 0, 0);

        // dot with d: element (ci, g, l31, 4kh+r); coalesced 512B/segment
        const f16* ddr = DfR + cb + l31 * 8 + 4 * kh;
        const f16* ddi = DfI + cb + l31 * 8 + 4 * kh;
        float part0 = 0.f, part1 = 0.f;
#pragma unroll
        for (int g = 0; g < 4; ++g) {
            const h4 dr = *(const h4*)(ddr + g * 256);
            const h4 di = *(const h4*)(ddi + g * 256);
#pragma unroll
            for (int r = 0; r < 4; ++r) {
                part0 = fmaf((float)dr[r], Tr[4 * g + r], part0);
                part1 = fmaf((float)di[r], Ti[4 * g + r], part1);
            }
        }
        float part = part0 + part1;
        part += __shfl_xor(part, 32, 64);

        const int p = ci * 32 + l31;
        const float lat = part - tau[p];
        const float lc  = fminf(fmaxf(lat, -15.f), 15.f);
        const float e   = __expf(2.f * lc);
        const float th  = __fdividef(e - 1.f, e + 1.f);
        const float lam = fmaxf(1e-6f, BETA_C * th);
        if (l < 32) lam_out[(size_t)b * NPX + p] = lam;
    }
}

// ---------------------------------------------------------------------------
// Kernel 2: partial out_b = A diag(lam) A^H; A fragments coalesced.
// Partials stored to ws — NO atomics.
// ---------------------------------------------------------------------------
__global__ __launch_bounds__(256) void outer_mfma(
    const f16* __restrict__ AfR, const f16* __restrict__ AfI,
    const float* __restrict__ lam_in, float* __restrict__ part)
{
    __shared__ float red[4][64][17];
    const int b   = blockIdx.y;
    const int t   = threadIdx.x;
    const int w   = t >> 6;
    const int l   = t & 63;
    const int kh  = l >> 5;

    f32x16 accRe = {}, accIm = {};

    const int base = blockIdx.x * CPB;
    const int end  = min(NCHUNKS, base + CPB);
    for (int ci = base + w; ci < end; ci += 4) {
        const size_t cb = (size_t)ci * 1024;
        const h8 ar0 = *(const h8*)(AfR + cb + l * 8);
        const h8 ar1 = *(const h8*)(AfR + cb + 512 + l * 8);
        const h8 ai0 = *(const h8*)(AfI + cb + l * 8);
        const h8 ai1 = *(const h8*)(AfI + cb + 512 + l * 8);

        const int pk = ci * 32 + 8 * kh;
        const float* lp = lam_in + (size_t)b * NPX + pk;
        const float4 la = *(const float4*)(lp);
        const float4 lb = *(const float4*)(lp + 4);
        const float4 lc = *(const float4*)(lp + 16);
        const float4 ld = *(const float4*)(lp + 20);
        const h2 q0 = pk_f16(la.x, la.y);
        const h2 q1 = pk_f16(la.z, la.w);
        const h2 q2 = pk_f16(lb.x, lb.y);
        const h2 q3 = pk_f16(lb.z, lb.w);
        const h2 q4 = pk_f16(lc.x, lc.y);
        const h2 q5 = pk_f16(lc.z, lc.w);
        const h2 q6 = pk_f16(ld.x, ld.y);
        const h2 q7 = pk_f16(ld.z, ld.w);
        const h8 lam0 = {q0[0], q0[1], q1[0], q1[1], q2[0], q2[1], q3[0], q3[1]};
        const h8 lam1 = {q4[0], q4[1], q5[0], q5[1], q6[0], q6[1], q7[0], q7[1]};

        const h8 vr0 = ar0 * lam0;   // v_pk_mul_f16 x4 each
        const h8 vi0 = ai0 * lam0;
        const h8 vr1 = ar1 * lam1;
        const h8 vi1 = ai1 * lam1;
        const h8 nvr0 = __builtin_bit_cast(h8, __builtin_bit_cast(short8, vr0) ^ (short)0x8000);
        const h8 nvr1 = __builtin_bit_cast(h8, __builtin_bit_cast(short8, vr1) ^ (short)0x8000);

        accRe = __builtin_amdgcn_mfma_f32_32x32x16_f16(vr0,  ar0, accRe, 0, 0, 0);
        accIm = __builtin_amdgcn_mfma_f32_32x32x16_f16(vi0,  ar0, accIm, 0, 0, 0);
        accRe = __builtin_amdgcn_mfma_f32_32x32x16_f16(vi0,  ai0, accRe, 0, 0, 0);
        accIm = __builtin_amdgcn_mfma_f32_32x32x16_f16(nvr0, ai0, accIm, 0, 0, 0);
        accRe = __builtin_amdgcn_mfma_f32_32x32x16_f16(vr1,  ar1, accRe, 0, 0, 0);
        accIm = __builtin_amdgcn_mfma_f32_32x32x16_f16(vi1,  ar1, accIm, 0, 0, 0);
        accRe = __builtin_amdgcn_mfma_f32_32x32x16_f16(vi1,  ai1, accRe, 0, 0, 0);
        accIm = __builtin_amdgcn_mfma_f32_32x32x16_f16(nvr1, ai1, accIm, 0, 0, 0);
    }

    // cross-wave reduce, then plain stores of the mapped partial (no atomics)
    float* pb = part + ((size_t)b * OB + blockIdx.x) * 2048;
#pragma unroll
    for (int r = 0; r < 16; ++r) red[w][l][r] = accRe[r];
    __syncthreads();
#pragma unroll
    for (int q = 0; q < 4; ++q) {
        const int idx = t + 256 * q;
        const int ll = idx >> 4, rr = idx & 15;
        const float s = red[0][ll][rr] + red[1][ll][rr] + red[2][ll][rr] + red[3][ll][rr];
        const int col  = ll & 31;
        const int orow = (rr & 3) + 8 * (rr >> 2) + 4 * (ll >> 5);
        pb[orow * 32 + col] = s;
    }
    __syncthreads();
#pragma unroll
    for (int r = 0; r < 16; ++r) red[w][l][r] = accIm[r];
    __syncthreads();
#pragma unroll
    for (int q = 0; q < 4; ++q) {
        const int idx = t + 256 * q;
        const int ll = idx >> 4, rr = idx & 15;
        const float s = red[0][ll][rr] + red[1][ll][rr] + red[2][ll][rr] + red[3][ll][rr];
        const int col  = ll & 31;
        const int orow = (rr & 3) + 8 * (rr >> 2) + 4 * (ll >> 5);
        pb[1024 + orow * 32 + col] = s;
    }
}

// ---------------------------------------------------------------------------
// Kernel 3: sum the OB partials per batch -> out planes (coalesced).
// ---------------------------------------------------------------------------
__global__ __launch_bounds__(256) void reduce_kernel(
    const float* __restrict__ part,
    float* __restrict__ out_re, float* __restrict__ out_im)
{
    const int b = blockIdx.x;
    const int t = threadIdx.x;
#pragma unroll
    for (int q = 0; q < 4; ++q) {
        const int slot = q * 256 + t;
        float sr = 0.f, si = 0.f;
        for (int k = 0; k < OB; ++k) {
            const float* pb = part + ((size_t)b * OB + k) * 2048;
            sr += pb[slot];
            si += pb[1024 + slot];
        }
        out_re[(size_t)b * 1024 + slot] = sr;
        if (out_im) out_im[(size_t)b * 1024 + slot] = si;
    }
}

// ---------------------------------------------------------------------------
extern "C" void kernel_launch(void* const* d_in, const int* in_sizes, int n_in,
                              void* d_out, int out_size, void* d_ws, size_t ws_size,
                              hipStream_t stream) {
    const float* S_real = (const float*)d_in[0];
    const float* S_imag = (const float*)d_in[1];
    const float* tau    = (const float*)d_in[2];
    const float* D_real = (const float*)d_in[3];
    const float* D_imag = (const float*)d_in[4];
    const float* A_real = (const float*)d_in[5];
    const float* A_imag = (const float*)d_in[6];

    // ws: AfR | AfI | DfR | DfI (f16 fragment planes, 5.12 MB) | partials
    f16* AfR = (f16*)d_ws;
    f16* AfI = AfR + (size_t)NCH * NPX;
    f16* DfR = AfI + (size_t)NCH * NPX;
    f16* DfI = DfR + (size_t)NCH * NPX;
    float* part = (float*)(DfI + (size_t)NCH * NPX);

    const size_t LAT = (size_t)B_SZ * NPX;        // 1,280,000
    const size_t RE  = (size_t)B_SZ * NCH * NCH;  // 65,536
    const size_t lam_off = (size_t)out_size - LAT;
    float* out_re = (float*)d_out;
    float* lam    = out_re + lam_off;
    float* out_im = (lam_off >= 2 * RE) ? out_re + RE : nullptr;

    prep_kernel<<<dim3(79), 256, 0, stream>>>(
        A_real, A_imag, D_real, D_imag, AfR, AfI, DfR, DfI);

    latent_mfma<<<dim3(OB, B_SZ), 256, 0, stream>>>(
        S_real, S_imag, tau, DfR, DfI, lam);

    outer_mfma<<<dim3(OB, B_SZ), 256, 0, stream>>>(
        AfR, AfI, lam, part);

    reduce_kernel<<<dim3(B_SZ), 256, 0, stream>>>(part, out_re, out_im);
}